// Round 1
// baseline (1692.169 us; speedup 1.0000x reference)
//
#include <hip/hip_runtime.h>

#define IGNORE_INDEX (-100)
#define VOCAB 32000
#define DDIM  2048
#define MTOK  8192   /* B*S = 4*2048 */

#define BM 128
#define BN 128
#define BK 32        /* bf16 elems per K-tile; 64 B per row */

typedef __bf16 bf16x8 __attribute__((ext_vector_type(8)));
typedef float  f32x4  __attribute__((ext_vector_type(4)));
typedef unsigned short ushortx8 __attribute__((ext_vector_type(8)));
typedef unsigned short ushort_t;

__device__ __forceinline__ unsigned short f2bf(float f) {
    unsigned u = __builtin_bit_cast(unsigned, f);
    u += 0x7fffu + ((u >> 16) & 1u);   // round-to-nearest-even
    return (unsigned short)(u >> 16);
}

// ---------------- fp32 -> bf16 conversion (8 elems/thread) ----------------
__global__ void cvt_f32_bf16(const float4* __restrict__ src,
                             ushortx8* __restrict__ dst) {
    size_t i = (size_t)blockIdx.x * blockDim.x + threadIdx.x;
    float4 a = src[2 * i];
    float4 b = src[2 * i + 1];
    ushortx8 o;
    o[0] = f2bf(a.x); o[1] = f2bf(a.y); o[2] = f2bf(a.z); o[3] = f2bf(a.w);
    o[4] = f2bf(b.x); o[5] = f2bf(b.y); o[6] = f2bf(b.z); o[7] = f2bf(b.w);
    dst[i] = o;
}

// ---------------- async global -> LDS (16 B per lane) ----------------
__device__ __forceinline__ void load_lds16(const ushort_t* g, ushort_t* l) {
    __builtin_amdgcn_global_load_lds(
        (const __attribute__((address_space(1))) unsigned int*)(const void*)g,
        (__attribute__((address_space(3))) unsigned int*)(void*)l,
        16, 0, 0);
}

// ---------------- fused GEMM + CE partial reduction ----------------
// A: hidden bf16 [MTOK][DDIM], B: weight bf16 [VOCAB][DDIM]
// For each token row m in this block's 128 rows:
//   atomicAdd(sumexp[m], sum_j exp(logit[m][j])) over this block's 128 cols
//   if targets[m] in this block's col range: tgtlogit[m] = logit[m][targets[m]]
__global__ __launch_bounds__(256) void gemm_ce(
    const ushort_t* __restrict__ A,
    const ushort_t* __restrict__ B,
    const int* __restrict__ targets,
    float* __restrict__ sumexp,
    float* __restrict__ tgtlogit) {
    __shared__ alignas(16) ushort_t As[BM * BK];   // 8 KiB
    __shared__ alignas(16) ushort_t Bs[BN * BK];   // 8 KiB

    const int tid  = threadIdx.x;
    const int wave = tid >> 6;
    const int lane = tid & 63;
    const int quad = lane >> 4;
    const int l16  = lane & 15;
    const int wm   = (wave >> 1) * 64;   // wave's row offset in 128x128 tile
    const int wn   = (wave & 1) * 64;    // wave's col offset

    const int m0 = blockIdx.x * BM;
    const int n0 = blockIdx.y * BN;

    const ushort_t* Ab = A + (size_t)m0 * DDIM;
    const ushort_t* Bb = B + (size_t)n0 * DDIM;

    // staging pattern: per wave per iter, 64 lanes x 16 B = 16 rows of 64 B
    const int srow = wave * 16 + (lane >> 2);   // row within 64-row half
    const int scol = (lane & 3) * 8;            // bf16-elem offset within row

    f32x4 acc[4][4];
    const f32x4 zero = {0.f, 0.f, 0.f, 0.f};
#pragma unroll
    for (int i = 0; i < 4; ++i)
#pragma unroll
        for (int j = 0; j < 4; ++j) acc[i][j] = zero;

    for (int k0 = 0; k0 < DDIM; k0 += BK) {
#pragma unroll
        for (int it = 0; it < 2; ++it) {
            load_lds16(Ab + (size_t)(it * 64 + srow) * DDIM + k0 + scol,
                       &As[(it * 64 + wave * 16) * BK]);
            load_lds16(Bb + (size_t)(it * 64 + srow) * DDIM + k0 + scol,
                       &Bs[(it * 64 + wave * 16) * BK]);
        }
        __syncthreads();   // drains vmcnt -> staging visible

        bf16x8 af[4], bfr[4];
#pragma unroll
        for (int i = 0; i < 4; ++i)
            af[i] = *reinterpret_cast<const bf16x8*>(
                &As[(wm + i * 16 + l16) * BK + quad * 8]);
#pragma unroll
        for (int j = 0; j < 4; ++j)
            bfr[j] = *reinterpret_cast<const bf16x8*>(
                &Bs[(wn + j * 16 + l16) * BK + quad * 8]);
#pragma unroll
        for (int i = 0; i < 4; ++i)
#pragma unroll
            for (int j = 0; j < 4; ++j)
                acc[i][j] = __builtin_amdgcn_mfma_f32_16x16x32_bf16(
                    af[i], bfr[j], acc[i][j], 0, 0, 0);
        __syncthreads();   // protect LDS before next staging
    }

    // Epilogue. C/D layout (verified m89/m91): row = quad*4 + reg, col = lane&15.
#pragma unroll
    for (int i = 0; i < 4; ++i) {
#pragma unroll
        for (int r = 0; r < 4; ++r) {
            const int mg = m0 + wm + i * 16 + quad * 4 + r;
            const int t  = targets[mg];
            float p = 0.f;
#pragma unroll
            for (int j = 0; j < 4; ++j) {
                float v = acc[i][j][r];
                p += __expf(v);
                if (t == n0 + wn + j * 16 + l16) tgtlogit[mg] = v;
            }
            // reduce across the 16 lanes sharing this row (same quad)
            p += __shfl_xor(p, 1);
            p += __shfl_xor(p, 2);
            p += __shfl_xor(p, 4);
            p += __shfl_xor(p, 8);
            if (l16 == 0) atomicAdd(&sumexp[mg], p);
        }
    }
}

// ---------------- final reduction: loss = sum(log(sumexp)-tgt)/n_valid ------
__global__ void finalize(const float* __restrict__ sumexp,
                         const float* __restrict__ tgtlogit,
                         const int* __restrict__ targets,
                         float* __restrict__ out) {
    __shared__ float s_sum[8];
    __shared__ float s_cnt[8];
    float local = 0.f, cnt = 0.f;
    for (int t = threadIdx.x; t < MTOK; t += blockDim.x) {
        int tg = targets[t];
        if (tg != IGNORE_INDEX) {
            local += logf(sumexp[t]) - tgtlogit[t];
            cnt += 1.f;
        }
    }
#pragma unroll
    for (int o = 32; o > 0; o >>= 1) {
        local += __shfl_down(local, o);
        cnt   += __shfl_down(cnt, o);
    }
    const int wave = threadIdx.x >> 6, lane = threadIdx.x & 63;
    if (lane == 0) { s_sum[wave] = local; s_cnt[wave] = cnt; }
    __syncthreads();
    if (threadIdx.x == 0) {
        float ts = 0.f, tc = 0.f;
        for (int w = 0; w < (int)(blockDim.x >> 6); ++w) {
            ts += s_sum[w];
            tc += s_cnt[w];
        }
        out[0] = (tc > 0.f) ? (ts / tc) : ts;
    }
}

extern "C" void kernel_launch(void* const* d_in, const int* in_sizes, int n_in,
                              void* d_out, int out_size, void* d_ws,
                              size_t ws_size, hipStream_t stream) {
    const float* weight  = (const float*)d_in[0];   // [VOCAB][DDIM] fp32
    const float* hidden  = (const float*)d_in[1];   // [MTOK][DDIM] fp32
    const int*   targets = (const int*)d_in[2];     // [MTOK]
    float* out = (float*)d_out;

    const size_t wbytes = (size_t)VOCAB * DDIM * 2;   // 131,072,000
    const size_t hbytes = (size_t)MTOK * DDIM * 2;    //  33,554,432
    ushort_t* Wb = (ushort_t*)d_ws;
    ushort_t* Hb = (ushort_t*)((char*)d_ws + wbytes);
    float* sumexp   = (float*)((char*)d_ws + wbytes + hbytes);
    float* tgtlogit = sumexp + MTOK;

    // fp32 -> bf16 conversions (exact-fit grids: elems % (256*8) == 0)
    cvt_f32_bf16<<<(VOCAB * (size_t)DDIM) / (256 * 8), 256, 0, stream>>>(
        (const float4*)weight, (ushortx8*)Wb);
    cvt_f32_bf16<<<(MTOK * (size_t)DDIM) / (256 * 8), 256, 0, stream>>>(
        (const float4*)hidden, (ushortx8*)Hb);

    // zero the accumulators (ws is poisoned 0xAA each call)
    hipMemsetAsync(sumexp, 0, 2 * MTOK * sizeof(float), stream);

    dim3 grid(MTOK / BM, VOCAB / BN);   // 64 x 250
    gemm_ce<<<grid, 256, 0, stream>>>(Hb, Wb, targets, sumexp, tgtlogit);

    finalize<<<1, 512, 0, stream>>>(sumexp, tgtlogit, targets, out);
}